// Round 2
// baseline (9254.294 us; speedup 1.0000x reference)
//
#include <hip/hip_runtime.h>
#include <hip/hip_bf16.h>

// LSTM autoencoder, 4 layers pipelined diagonally across timesteps.
// 56 persistent workgroups (plain launch, 56 <= 256 CUs with
// __launch_bounds__(256,1) -> all co-resident), weights held in VGPRs as
// MFMA B-fragments, c-state in registers, h exchanged via tiny global
// double-buffers. Sync: per-WG monotonic flag + lane-parallel poll barrier.

typedef __bf16 bf16x8 __attribute__((ext_vector_type(8)));
typedef float f32x4 __attribute__((ext_vector_type(4)));

#define NWG 56
#define TSTEPS 1024
#define NSTEPS (TSTEPS + 3)

__device__ __forceinline__ f32x4 mfma16(bf16x8 a, bf16x8 b, f32x4 c) {
  return __builtin_amdgcn_mfma_f32_16x16x32_bf16(a, b, c, 0, 0, 0);
}

__device__ __forceinline__ float sigmoid_fast(float x) {
  return 1.0f / (1.0f + __expf(-x));
}

// Device-scope barrier: each WG posts step count to its own flag (own cache
// line), wave 0 polls all 56 flags with one lane-parallel load + ballot.
// Release: __threadfence (L2 writeback) before post — covers whole WG's
// stores since __syncthreads drains vmcnt. Acquire: __threadfence (L1/L2
// invalidate) after poll, ordered before other waves' loads by syncthreads.
__device__ __forceinline__ void grid_barrier(unsigned* flags, int wg,
                                             unsigned target) {
  __syncthreads();
  if (threadIdx.x < 64) {
    __threadfence();  // release
    if (threadIdx.x == 0)
      __hip_atomic_store(&flags[wg * 32], target, __ATOMIC_RELAXED,
                         __HIP_MEMORY_SCOPE_AGENT);
    const int idx = (threadIdx.x < NWG) ? (int)threadIdx.x : 0;
    while (true) {
      unsigned v = __hip_atomic_load(&flags[idx * 32], __ATOMIC_RELAXED,
                                     __HIP_MEMORY_SCOPE_AGENT);
      if (!__ballot(v < target)) break;
      __builtin_amdgcn_s_sleep(1);
    }
    __threadfence();  // acquire
  }
  __syncthreads();
}

// One LSTM layer, one gate-column slice (16 h-columns x 4 gates = 64 cols).
// Wave w handles batch rows [16w,16w+16). Each lane keeps c-state for its 4
// (row,hcol) cells; W/U fragments live in VGPRs for the whole kernel.
template <int F, int H, int LAYER>
__device__ void layer_loop(const float* __restrict__ xg,   // LAYER==1: x [64][1024][256]
                           const __bf16* __restrict__ xin, // LAYER>1: prev h [2][64][F]
                           const float* __restrict__ W,    // [F][4H]
                           const float* __restrict__ U,    // [H][4H]
                           const float* __restrict__ bias_g, // [4H]
                           __bf16* __restrict__ hbuf,      // own h [2][64][H]
                           float* __restrict__ out,        // LAYER==4: [64][1024][256]
                           unsigned* flags, int wg, int slice, __bf16* smem) {
  constexpr int KW = F / 32;
  constexpr int KU = H / 32;
  constexpr int FOURH = 4 * H;
  const int tid = threadIdx.x;
  const int wave = tid >> 6;
  const int lane = tid & 63;
  const int l15 = lane & 15;
  const int q = lane >> 4;
  const int hcol = slice * 16 + l15;
  const int brow = wave * 16;

  float bz[4];
#pragma unroll
  for (int nt = 0; nt < 4; ++nt) bz[nt] = bias_g[nt * H + hcol];

  // ---- one-time: stage W slice to LDS (coalesced), extract B-frags to regs ----
  bf16x8 wf[4][KW];
  bf16x8 uf[4][KU];
  for (int idx = tid; idx < F * 64; idx += 256) {
    int k = idx >> 6, c = idx & 63;
    int col = (c >> 4) * H + slice * 16 + (c & 15);
    smem[c * F + k] = (__bf16)W[k * FOURH + col];
  }
  __syncthreads();
#pragma unroll
  for (int nt = 0; nt < 4; ++nt)
#pragma unroll
    for (int kk = 0; kk < KW; ++kk)
      wf[nt][kk] = *(const bf16x8*)&smem[(nt * 16 + l15) * F + kk * 32 + q * 8];
  __syncthreads();
  for (int idx = tid; idx < H * 64; idx += 256) {
    int k = idx >> 6, c = idx & 63;
    int col = (c >> 4) * H + slice * 16 + (c & 15);
    smem[c * H + k] = (__bf16)U[k * FOURH + col];
  }
  __syncthreads();
#pragma unroll
  for (int nt = 0; nt < 4; ++nt)
#pragma unroll
    for (int kk = 0; kk < KU; ++kk)
      uf[nt][kk] = *(const bf16x8*)&smem[(nt * 16 + l15) * H + kk * 32 + q * 8];

  float c_state[4] = {0.f, 0.f, 0.f, 0.f};

  for (int s = 0; s < NSTEPS; ++s) {
    const int t = s - (LAYER - 1);
    if (t >= 0 && t < TSTEPS) {
      f32x4 acc[4] = {};
      // ---- input projection: z += x(t) @ W ----
      if (LAYER == 1) {
        const float* xrow = xg + ((size_t)(brow + l15) * 1024 + t) * 256 + q * 8;
#pragma unroll
        for (int kk = 0; kk < KW; ++kk) {
          const float4* p = (const float4*)(xrow + kk * 32);
          float4 a0 = p[0], a1 = p[1];
          bf16x8 a;
          a[0] = (__bf16)a0.x; a[1] = (__bf16)a0.y;
          a[2] = (__bf16)a0.z; a[3] = (__bf16)a0.w;
          a[4] = (__bf16)a1.x; a[5] = (__bf16)a1.y;
          a[6] = (__bf16)a1.z; a[7] = (__bf16)a1.w;
#pragma unroll
          for (int nt = 0; nt < 4; ++nt) acc[nt] = mfma16(a, wf[nt][kk], acc[nt]);
        }
      } else {
        const __bf16* xr = xin + ((size_t)(t & 1) * 64 + brow + l15) * F + q * 8;
#pragma unroll
        for (int kk = 0; kk < KW; ++kk) {
          bf16x8 a = *(const bf16x8*)(xr + kk * 32);
#pragma unroll
          for (int nt = 0; nt < 4; ++nt) acc[nt] = mfma16(a, wf[nt][kk], acc[nt]);
        }
      }
      // ---- recurrent projection: z += h(t-1) @ U ----
      if (t > 0) {
        const __bf16* hr = hbuf + ((size_t)((t - 1) & 1) * 64 + brow + l15) * H + q * 8;
#pragma unroll
        for (int kk = 0; kk < KU; ++kk) {
          bf16x8 a = *(const bf16x8*)(hr + kk * 32);
#pragma unroll
          for (int nt = 0; nt < 4; ++nt) acc[nt] = mfma16(a, uf[nt][kk], acc[nt]);
        }
      }
      // ---- gates + state update (all lane-local) ----
      __bf16* hw = hbuf + (size_t)(t & 1) * 64 * H;
#pragma unroll
      for (int r = 0; r < 4; ++r) {
        float zi = acc[0][r] + bz[0];
        float zf = acc[1][r] + bz[1];
        float zg = acc[2][r] + bz[2];
        float zo = acc[3][r] + bz[3];
        float ig = sigmoid_fast(zi);
        float fg = sigmoid_fast(zf);
        float gg = fmaxf(zg, 0.0f);
        float og = sigmoid_fast(zo);
        float cn = fg * c_state[r] + ig * gg;
        c_state[r] = cn;
        float hv = og * fmaxf(cn, 0.0f);
        int b = brow + q * 4 + r;
        hw[b * H + hcol] = (__bf16)hv;
        if (LAYER == 4) out[((size_t)b * 1024 + t) * 256 + hcol] = hv;
      }
    }
    grid_barrier(flags, wg, (unsigned)(s + 1));
  }
}

struct KParams {
  const float* x;
  const float* W1; const float* U1; const float* b1;
  const float* W2; const float* U2; const float* b2;
  const float* W3; const float* U3; const float* b3;
  const float* W4; const float* U4; const float* b4;
  float* out;
  unsigned* flags;
  void* h1; void* h2; void* h3; void* h4;
};

__global__ __launch_bounds__(256, 1) void lstm_kernel(KParams p) {
  __shared__ __align__(16) __bf16 smem[64 * 256];  // 32 KB staging for weight slices
  int wg = blockIdx.x;
  if (wg < 16)
    layer_loop<256, 256, 1>(p.x, nullptr, p.W1, p.U1, p.b1, (__bf16*)p.h1,
                            nullptr, p.flags, wg, wg, smem);
  else if (wg < 24)
    layer_loop<256, 128, 2>(nullptr, (const __bf16*)p.h1, p.W2, p.U2, p.b2,
                            (__bf16*)p.h2, nullptr, p.flags, wg, wg - 16, smem);
  else if (wg < 40)
    layer_loop<128, 256, 3>(nullptr, (const __bf16*)p.h2, p.W3, p.U3, p.b3,
                            (__bf16*)p.h3, nullptr, p.flags, wg, wg - 24, smem);
  else
    layer_loop<256, 256, 4>(nullptr, (const __bf16*)p.h3, p.W4, p.U4, p.b4,
                            (__bf16*)p.h4, p.out, p.flags, wg, wg - 40, smem);
}

extern "C" void kernel_launch(void* const* d_in, const int* in_sizes, int n_in,
                              void* d_out, int out_size, void* d_ws, size_t ws_size,
                              hipStream_t stream) {
  unsigned char* ws = (unsigned char*)d_ws;
  KParams p;
  p.x  = (const float*)d_in[0];
  p.W1 = (const float*)d_in[1];  p.U1 = (const float*)d_in[2];  p.b1 = (const float*)d_in[3];
  p.W2 = (const float*)d_in[4];  p.U2 = (const float*)d_in[5];  p.b2 = (const float*)d_in[6];
  p.W3 = (const float*)d_in[7];  p.U3 = (const float*)d_in[8];  p.b3 = (const float*)d_in[9];
  p.W4 = (const float*)d_in[10]; p.U4 = (const float*)d_in[11]; p.b4 = (const float*)d_in[12];
  p.out = (float*)d_out;
  p.flags = (unsigned*)ws;                 // 56 flags, 128 B apart (7168 B)
  size_t off = 8192;
  p.h1 = (void*)(ws + off); off += (size_t)2 * 64 * 256 * 2;
  p.h2 = (void*)(ws + off); off += (size_t)2 * 64 * 128 * 2;
  p.h3 = (void*)(ws + off); off += (size_t)2 * 64 * 256 * 2;
  p.h4 = (void*)(ws + off);

  hipMemsetAsync(d_ws, 0, 8192, stream);   // zero the barrier flags

  lstm_kernel<<<dim3(NWG), dim3(256), 0, stream>>>(p);
}

// Round 3
// 8021.629 us; speedup vs baseline: 1.1537x; 1.1537x over previous
//
#include <hip/hip_runtime.h>
#include <hip/hip_bf16.h>

// LSTM autoencoder, 4 layers pipelined diagonally across timesteps.
// 56 persistent workgroups, weights in VGPR/AGPR MFMA B-fragments, c-state in
// registers. Cross-WG h exchange via relaxed AGENT-scope 8B atomics (coherent
// at LLC, no threadfence -> no per-step buffer_wbl2/buffer_inv L2 nukes).
// Per-WG monotonic step flags; every wave polls all 56 flags lane-parallel.

typedef __bf16 bf16x8 __attribute__((ext_vector_type(8)));
typedef float f32x4 __attribute__((ext_vector_type(4)));
typedef unsigned long long u64;

#define NWG 56
#define TSTEPS 1024
#define NSTEPS (TSTEPS + 3)

__device__ __forceinline__ f32x4 mfma16(bf16x8 a, bf16x8 b, f32x4 c) {
  return __builtin_amdgcn_mfma_f32_16x16x32_bf16(a, b, c, 0, 0, 0);
}

__device__ __forceinline__ float sigmoid_fast(float x) {
  return 1.0f / (1.0f + __expf(-x));
}

// 16B MFMA A-fragment via two 8B LLC-coherent (agent-scope) atomic loads.
__device__ __forceinline__ bf16x8 load_frag_llc(const __bf16* p) {
  union { bf16x8 v; u64 d[2]; } u;
  u.d[0] = __hip_atomic_load((const u64*)p, __ATOMIC_RELAXED,
                             __HIP_MEMORY_SCOPE_AGENT);
  u.d[1] = __hip_atomic_load((const u64*)(p + 4), __ATOMIC_RELAXED,
                             __HIP_MEMORY_SCOPE_AGENT);
  return u.v;
}

__device__ __forceinline__ void store8_llc(__bf16* p, u64 v) {
  __hip_atomic_store((u64*)p, v, __ATOMIC_RELAXED, __HIP_MEMORY_SCOPE_AGENT);
}

// Wait until every WG has completed macro-step s-1 (flag >= s). Per-wave,
// lane-parallel over the 56 flags; no fences (all shared data is atomic).
__device__ __forceinline__ void poll_flags(unsigned* flags, unsigned s) {
  const int lane = threadIdx.x & 63;
  const int idx = (lane < NWG) ? lane : 0;
  while (true) {
    unsigned v = __hip_atomic_load(&flags[idx * 32], __ATOMIC_RELAXED,
                                   __HIP_MEMORY_SCOPE_AGENT);
    if (!__ballot(v < s)) break;
    __builtin_amdgcn_s_sleep(1);
  }
}

// One LSTM layer, one gate-column slice (16 h-columns x 4 gates = 64 cols).
// Wave w handles batch rows [16w,16w+16). Each lane keeps c-state for its 4
// (row,hcol) cells; W/U fragments live in registers for the whole kernel.
template <int F, int H, int LAYER>
__device__ void layer_loop(const float* __restrict__ xg,   // LAYER==1: x [64][1024][256]
                           const __bf16* __restrict__ xin, // LAYER>1: prev h [2][64][F]
                           const float* __restrict__ W,    // [F][4H]
                           const float* __restrict__ U,    // [H][4H]
                           const float* __restrict__ bias_g, // [4H]
                           __bf16* __restrict__ hbuf,      // own h [2][64][H]
                           float* __restrict__ out,        // LAYER==4: [64][1024][256]
                           unsigned* flags, int wg, int slice, __bf16* smem) {
  constexpr int KW = F / 32;
  constexpr int KU = H / 32;
  constexpr int FOURH = 4 * H;
  const int tid = threadIdx.x;
  const int wave = tid >> 6;
  const int lane = tid & 63;
  const int l15 = lane & 15;
  const int q = lane >> 4;
  const int hcol = slice * 16 + l15;
  const int brow = wave * 16;

  float bz[4];
#pragma unroll
  for (int nt = 0; nt < 4; ++nt) bz[nt] = bias_g[nt * H + hcol];

  // ---- one-time: stage W slice to LDS (coalesced), extract B-frags to regs ----
  bf16x8 wf[4][KW];
  bf16x8 uf[4][KU];
  for (int idx = tid; idx < F * 64; idx += 256) {
    int k = idx >> 6, c = idx & 63;
    int col = (c >> 4) * H + slice * 16 + (c & 15);
    smem[c * F + k] = (__bf16)W[k * FOURH + col];
  }
  __syncthreads();
#pragma unroll
  for (int nt = 0; nt < 4; ++nt)
#pragma unroll
    for (int kk = 0; kk < KW; ++kk)
      wf[nt][kk] = *(const bf16x8*)&smem[(nt * 16 + l15) * F + kk * 32 + q * 8];
  __syncthreads();
  for (int idx = tid; idx < H * 64; idx += 256) {
    int k = idx >> 6, c = idx & 63;
    int col = (c >> 4) * H + slice * 16 + (c & 15);
    smem[c * H + k] = (__bf16)U[k * FOURH + col];
  }
  __syncthreads();
#pragma unroll
  for (int nt = 0; nt < 4; ++nt)
#pragma unroll
    for (int kk = 0; kk < KU; ++kk)
      uf[nt][kk] = *(const bf16x8*)&smem[(nt * 16 + l15) * H + kk * 32 + q * 8];
  __syncthreads();

  // LDS region reused as 64x16 bf16 transpose tile for packed h stores.
  __bf16* hlds = smem;

  float c_state[4] = {0.f, 0.f, 0.f, 0.f};

  for (int s = 0; s < NSTEPS; ++s) {
    const int t = s - (LAYER - 1);
    const bool active = (t >= 0) & (t < TSTEPS);
    // Everyone completed step s-1 => h(t-1) posted, prev-layer h(t) posted,
    // and the h(t-2) slot we are about to overwrite has been consumed.
    poll_flags(flags, (unsigned)s);
    float hv[4];
    if (active) {
      f32x4 acc[4] = {};
      // ---- input projection: z += x(t) @ W ----
      if (LAYER == 1) {
        const float* xrow = xg + ((size_t)(brow + l15) * 1024 + t) * 256 + q * 8;
#pragma unroll
        for (int kk = 0; kk < KW; ++kk) {
          const float4* p = (const float4*)(xrow + kk * 32);
          float4 a0 = p[0], a1 = p[1];
          bf16x8 a;
          a[0] = (__bf16)a0.x; a[1] = (__bf16)a0.y;
          a[2] = (__bf16)a0.z; a[3] = (__bf16)a0.w;
          a[4] = (__bf16)a1.x; a[5] = (__bf16)a1.y;
          a[6] = (__bf16)a1.z; a[7] = (__bf16)a1.w;
#pragma unroll
          for (int nt = 0; nt < 4; ++nt) acc[nt] = mfma16(a, wf[nt][kk], acc[nt]);
        }
      } else {
        const __bf16* xr = xin + ((size_t)(t & 1) * 64 + brow + l15) * F + q * 8;
#pragma unroll
        for (int kk = 0; kk < KW; ++kk) {
          bf16x8 a = load_frag_llc(xr + kk * 32);
#pragma unroll
          for (int nt = 0; nt < 4; ++nt) acc[nt] = mfma16(a, wf[nt][kk], acc[nt]);
        }
      }
      // ---- recurrent projection: z += h(t-1) @ U ----
      if (t > 0) {
        const __bf16* hr = hbuf + ((size_t)((t - 1) & 1) * 64 + brow + l15) * H + q * 8;
#pragma unroll
        for (int kk = 0; kk < KU; ++kk) {
          bf16x8 a = load_frag_llc(hr + kk * 32);
#pragma unroll
          for (int nt = 0; nt < 4; ++nt) acc[nt] = mfma16(a, uf[nt][kk], acc[nt]);
        }
      }
      // ---- gates + state update (all lane-local) ----
#pragma unroll
      for (int r = 0; r < 4; ++r) {
        float zi = acc[0][r] + bz[0];
        float zf = acc[1][r] + bz[1];
        float zg = acc[2][r] + bz[2];
        float zo = acc[3][r] + bz[3];
        float ig = sigmoid_fast(zi);
        float fg = sigmoid_fast(zf);
        float gg = fmaxf(zg, 0.0f);
        float og = sigmoid_fast(zo);
        float cn = fg * c_state[r] + ig * gg;
        c_state[r] = cn;
        hv[r] = og * fmaxf(cn, 0.0f);
        // stage into 64x16 LDS tile for packed 8B coherent stores
        hlds[(brow + q * 4 + r) * 16 + l15] = (__bf16)hv[r];
      }
    }
    __syncthreads();  // transpose tile visible to all threads
    if (active) {
      // packed h store: thread tid owns row tid/4, col-group tid%4 (4 bf16)
      int row = tid >> 2, cg = tid & 3;
      u64 v = *(const u64*)&hlds[row * 16 + cg * 4];
      store8_llc(hbuf + ((size_t)(t & 1) * 64 + row) * H + slice * 16 + cg * 4, v);
      if (LAYER == 4) {
#pragma unroll
        for (int r = 0; r < 4; ++r) {
          int b = brow + q * 4 + r;
          out[((size_t)b * 1024 + t) * 256 + hcol] = hv[r];
        }
      }
    }
    __syncthreads();  // compiler drains vmcnt(0) here -> h stores at LLC
    if (tid == 0)
      __hip_atomic_store(&flags[wg * 32], (unsigned)(s + 1), __ATOMIC_RELAXED,
                         __HIP_MEMORY_SCOPE_AGENT);
  }
}

struct KParams {
  const float* x;
  const float* W1; const float* U1; const float* b1;
  const float* W2; const float* U2; const float* b2;
  const float* W3; const float* U3; const float* b3;
  const float* W4; const float* U4; const float* b4;
  float* out;
  unsigned* flags;
  void* h1; void* h2; void* h3; void* h4;
};

__global__ __launch_bounds__(256, 1) void lstm_kernel(KParams p) {
  __shared__ __align__(16) __bf16 smem[64 * 256];  // 32 KB staging
  int wg = blockIdx.x;
  if (wg < 16)
    layer_loop<256, 256, 1>(p.x, nullptr, p.W1, p.U1, p.b1, (__bf16*)p.h1,
                            nullptr, p.flags, wg, wg, smem);
  else if (wg < 24)
    layer_loop<256, 128, 2>(nullptr, (const __bf16*)p.h1, p.W2, p.U2, p.b2,
                            (__bf16*)p.h2, nullptr, p.flags, wg, wg - 16, smem);
  else if (wg < 40)
    layer_loop<128, 256, 3>(nullptr, (const __bf16*)p.h2, p.W3, p.U3, p.b3,
                            (__bf16*)p.h3, nullptr, p.flags, wg, wg - 24, smem);
  else
    layer_loop<256, 256, 4>(nullptr, (const __bf16*)p.h3, p.W4, p.U4, p.b4,
                            (__bf16*)p.h4, p.out, p.flags, wg, wg - 40, smem);
}

extern "C" void kernel_launch(void* const* d_in, const int* in_sizes, int n_in,
                              void* d_out, int out_size, void* d_ws, size_t ws_size,
                              hipStream_t stream) {
  unsigned char* ws = (unsigned char*)d_ws;
  KParams p;
  p.x  = (const float*)d_in[0];
  p.W1 = (const float*)d_in[1];  p.U1 = (const float*)d_in[2];  p.b1 = (const float*)d_in[3];
  p.W2 = (const float*)d_in[4];  p.U2 = (const float*)d_in[5];  p.b2 = (const float*)d_in[6];
  p.W3 = (const float*)d_in[7];  p.U3 = (const float*)d_in[8];  p.b3 = (const float*)d_in[9];
  p.W4 = (const float*)d_in[10]; p.U4 = (const float*)d_in[11]; p.b4 = (const float*)d_in[12];
  p.out = (float*)d_out;
  p.flags = (unsigned*)ws;                 // 56 flags, 128 B apart (7168 B)
  size_t off = 8192;
  p.h1 = (void*)(ws + off); off += (size_t)2 * 64 * 256 * 2;
  p.h2 = (void*)(ws + off); off += (size_t)2 * 64 * 128 * 2;
  p.h3 = (void*)(ws + off); off += (size_t)2 * 64 * 256 * 2;
  p.h4 = (void*)(ws + off);

  hipMemsetAsync(d_ws, 0, 8192, stream);   // zero the step flags

  lstm_kernel<<<dim3(NWG), dim3(256), 0, stream>>>(p);
}

// Round 4
// 7952.306 us; speedup vs baseline: 1.1637x; 1.0087x over previous
//
#include <hip/hip_runtime.h>
#include <hip/hip_bf16.h>

// LSTM autoencoder, 4 layers pipelined diagonally across timesteps.
// 56 persistent workgroups, weights in register MFMA B-fragments, c-state in
// registers. Cross-WG h exchange via relaxed AGENT-scope 8B atomics (LLC
// coherent, no fences). Sync: NEIGHBOR-ONLY waits (layers l-1,l,l+1 at s-1)
// on packed per-layer flag lines (1 line/layer, <=3 lines per poll).

typedef __bf16 bf16x8 __attribute__((ext_vector_type(8)));
typedef float f32x4 __attribute__((ext_vector_type(4)));
typedef unsigned long long u64;

#define NWG 56
#define TSTEPS 1024
#define NSTEPS (TSTEPS + 3)

// flags layout: flags[layer_base + slice], layer bases 32 uints (128 B) apart:
//   L1: 0..15, L2: 32..39, L3: 64..79, L4: 96..111
__device__ __constant__ const int kFlagCnt[6]  = {0, 16, 8, 16, 16, 0};
__device__ __constant__ const int kFlagBase[6] = {0, 0, 32, 64, 96, 0};

__device__ __forceinline__ f32x4 mfma16(bf16x8 a, bf16x8 b, f32x4 c) {
  return __builtin_amdgcn_mfma_f32_16x16x32_bf16(a, b, c, 0, 0, 0);
}

__device__ __forceinline__ float sigmoid_fast(float x) {
  return 1.0f / (1.0f + __expf(-x));
}

// 16B MFMA A-fragment via two 8B LLC-coherent (agent-scope) atomic loads.
__device__ __forceinline__ bf16x8 load_frag_llc(const __bf16* p) {
  union { bf16x8 v; u64 d[2]; } u;
  u.d[0] = __hip_atomic_load((const u64*)p, __ATOMIC_RELAXED,
                             __HIP_MEMORY_SCOPE_AGENT);
  u.d[1] = __hip_atomic_load((const u64*)(p + 4), __ATOMIC_RELAXED,
                             __HIP_MEMORY_SCOPE_AGENT);
  return u.v;
}

__device__ __forceinline__ void store8_llc(__bf16* p, u64 v) {
  __hip_atomic_store((u64*)p, v, __ATOMIC_RELAXED, __HIP_MEMORY_SCOPE_AGENT);
}

// Wait until layers {LAYER-1, LAYER, LAYER+1} have all finished step s-1
// (flag >= s). All waves poll; <=40 lanes over <=3 cache lines.
template <int LAYER>
__device__ __forceinline__ void wait_deps(unsigned* flags, unsigned s) {
  constexpr int n1 = (LAYER >= 2) ? ((LAYER - 1 == 2) ? 8 : 16) : 0;
  constexpr int n2 = (LAYER == 2) ? 8 : 16;
  constexpr int n3 = (LAYER <= 3) ? ((LAYER + 1 == 2) ? 8 : 16) : 0;
  constexpr int b1 = (LAYER >= 2) ? (LAYER - 2) * 32 : 0;
  constexpr int b2 = (LAYER - 1) * 32;
  constexpr int b3 = (LAYER <= 3) ? LAYER * 32 : 0;
  const int lane = threadIdx.x & 63;
  int fidx;
  if (lane < n1) fidx = b1 + lane;
  else if (lane < n1 + n2) fidx = b2 + (lane - n1);
  else if (lane < n1 + n2 + n3) fidx = b3 + (lane - n1 - n2);
  else fidx = b2;  // duplicate a same-layer flag; harmless
  unsigned* p = &flags[fidx];
  while (true) {
    unsigned v = __hip_atomic_load(p, __ATOMIC_RELAXED,
                                   __HIP_MEMORY_SCOPE_AGENT);
    if (!__ballot(v < s)) break;
  }
}

// One LSTM layer, one gate-column slice (16 h-columns x 4 gates = 64 cols).
// Wave w handles batch rows [16w,16w+16). Each lane keeps c-state for its 4
// (row,hcol) cells; W/U fragments live in registers for the whole kernel.
template <int F, int H, int LAYER>
__device__ void layer_loop(const float* __restrict__ xg,   // LAYER==1: x [64][1024][256]
                           const __bf16* __restrict__ xin, // LAYER>1: prev h [2][64][F]
                           const float* __restrict__ W,    // [F][4H]
                           const float* __restrict__ U,    // [H][4H]
                           const float* __restrict__ bias_g, // [4H]
                           __bf16* __restrict__ hbuf,      // own h [2][64][H]
                           float* __restrict__ out,        // LAYER==4: [64][1024][256]
                           unsigned* flags, int slice, __bf16* smem) {
  constexpr int KW = F / 32;
  constexpr int KU = H / 32;
  constexpr int FOURH = 4 * H;
  constexpr int MYFLAG_BASE = (LAYER - 1) * 32;
  const int tid = threadIdx.x;
  const int wave = tid >> 6;
  const int lane = tid & 63;
  const int l15 = lane & 15;
  const int q = lane >> 4;
  const int hcol = slice * 16 + l15;
  const int brow = wave * 16;

  float bz[4];
#pragma unroll
  for (int nt = 0; nt < 4; ++nt) bz[nt] = bias_g[nt * H + hcol];

  // ---- one-time: stage W slice to LDS (coalesced), extract B-frags to regs ----
  bf16x8 wf[4][KW];
  bf16x8 uf[4][KU];
  for (int idx = tid; idx < F * 64; idx += 256) {
    int k = idx >> 6, c = idx & 63;
    int col = (c >> 4) * H + slice * 16 + (c & 15);
    smem[c * F + k] = (__bf16)W[k * FOURH + col];
  }
  __syncthreads();
#pragma unroll
  for (int nt = 0; nt < 4; ++nt)
#pragma unroll
    for (int kk = 0; kk < KW; ++kk)
      wf[nt][kk] = *(const bf16x8*)&smem[(nt * 16 + l15) * F + kk * 32 + q * 8];
  __syncthreads();
  for (int idx = tid; idx < H * 64; idx += 256) {
    int k = idx >> 6, c = idx & 63;
    int col = (c >> 4) * H + slice * 16 + (c & 15);
    smem[c * H + k] = (__bf16)U[k * FOURH + col];
  }
  __syncthreads();
#pragma unroll
  for (int nt = 0; nt < 4; ++nt)
#pragma unroll
    for (int kk = 0; kk < KU; ++kk)
      uf[nt][kk] = *(const bf16x8*)&smem[(nt * 16 + l15) * H + kk * 32 + q * 8];
  __syncthreads();

  // LDS region reused as 64x16 bf16 transpose tile for packed h stores.
  __bf16* hlds = smem;

  float c_state[4] = {0.f, 0.f, 0.f, 0.f};

  for (int s = 0; s < NSTEPS; ++s) {
    const int t = s - (LAYER - 1);
    const bool active = (t >= 0) & (t < TSTEPS);

    // Layer 1: x(t) has no cross-WG dependency -> load+convert BEFORE the
    // wait so HBM latency hides behind the flag poll.
    bf16x8 a_pre[(LAYER == 1) ? KW : 1];
    if (LAYER == 1 && active) {
      const float* xrow = xg + ((size_t)(brow + l15) * 1024 + t) * 256 + q * 8;
#pragma unroll
      for (int kk = 0; kk < KW; ++kk) {
        const float4* p4 = (const float4*)(xrow + kk * 32);
        float4 a0 = p4[0], a1 = p4[1];
        bf16x8 a;
        a[0] = (__bf16)a0.x; a[1] = (__bf16)a0.y;
        a[2] = (__bf16)a0.z; a[3] = (__bf16)a0.w;
        a[4] = (__bf16)a1.x; a[5] = (__bf16)a1.y;
        a[6] = (__bf16)a1.z; a[7] = (__bf16)a1.w;
        a_pre[kk] = a;
      }
    }

    wait_deps<LAYER>(flags, (unsigned)s);

    float hv[4];
    if (active) {
      f32x4 acc[4] = {};
      // ---- input projection: z += x(t) @ W ----
      if (LAYER == 1) {
#pragma unroll
        for (int kk = 0; kk < KW; ++kk)
#pragma unroll
          for (int nt = 0; nt < 4; ++nt)
            acc[nt] = mfma16(a_pre[kk], wf[nt][kk], acc[nt]);
      } else {
        const __bf16* xr = xin + ((size_t)(t & 1) * 64 + brow + l15) * F + q * 8;
#pragma unroll
        for (int kk = 0; kk < KW; ++kk) {
          bf16x8 a = load_frag_llc(xr + kk * 32);
#pragma unroll
          for (int nt = 0; nt < 4; ++nt) acc[nt] = mfma16(a, wf[nt][kk], acc[nt]);
        }
      }
      // ---- recurrent projection: z += h(t-1) @ U ----
      if (t > 0) {
        const __bf16* hr = hbuf + ((size_t)((t - 1) & 1) * 64 + brow + l15) * H + q * 8;
#pragma unroll
        for (int kk = 0; kk < KU; ++kk) {
          bf16x8 a = load_frag_llc(hr + kk * 32);
#pragma unroll
          for (int nt = 0; nt < 4; ++nt) acc[nt] = mfma16(a, uf[nt][kk], acc[nt]);
        }
      }
      // ---- gates + state update (all lane-local) ----
#pragma unroll
      for (int r = 0; r < 4; ++r) {
        float zi = acc[0][r] + bz[0];
        float zf = acc[1][r] + bz[1];
        float zg = acc[2][r] + bz[2];
        float zo = acc[3][r] + bz[3];
        float ig = sigmoid_fast(zi);
        float fg = sigmoid_fast(zf);
        float gg = fmaxf(zg, 0.0f);
        float og = sigmoid_fast(zo);
        float cn = fg * c_state[r] + ig * gg;
        c_state[r] = cn;
        hv[r] = og * fmaxf(cn, 0.0f);
        // stage into 64x16 LDS tile for packed 8B coherent stores
        hlds[(brow + q * 4 + r) * 16 + l15] = (__bf16)hv[r];
      }
    }
    __syncthreads();  // A: transpose tile visible
    if (active) {
      // packed h store: thread tid owns row tid/4, col-group tid%4 (4 bf16)
      int row = tid >> 2, cg = tid & 3;
      u64 v = *(const u64*)&hlds[row * 16 + cg * 4];
      store8_llc(hbuf + ((size_t)(t & 1) * 64 + row) * H + slice * 16 + cg * 4, v);
    }
    __syncthreads();  // B: all waves' h stores vmcnt-drained (at LLC)
    if (tid == 0)
      __hip_atomic_store(&flags[MYFLAG_BASE + slice], (unsigned)(s + 1),
                         __ATOMIC_RELAXED, __HIP_MEMORY_SCOPE_AGENT);
    // Layer 4 output: fire-and-forget AFTER the post; drains during the
    // next step's slack instead of sitting on the critical chain.
    if (LAYER == 4 && active) {
#pragma unroll
      for (int r = 0; r < 4; ++r) {
        int b = brow + q * 4 + r;
        out[((size_t)b * 1024 + t) * 256 + hcol] = hv[r];
      }
    }
  }
}

struct KParams {
  const float* x;
  const float* W1; const float* U1; const float* b1;
  const float* W2; const float* U2; const float* b2;
  const float* W3; const float* U3; const float* b3;
  const float* W4; const float* U4; const float* b4;
  float* out;
  unsigned* flags;
  void* h1; void* h2; void* h3; void* h4;
};

__global__ __launch_bounds__(256, 1) void lstm_kernel(KParams p) {
  __shared__ __align__(16) __bf16 smem[64 * 256];  // 32 KB staging
  int wg = blockIdx.x;
  if (wg < 16)
    layer_loop<256, 256, 1>(p.x, nullptr, p.W1, p.U1, p.b1, (__bf16*)p.h1,
                            nullptr, p.flags, wg, smem);
  else if (wg < 24)
    layer_loop<256, 128, 2>(nullptr, (const __bf16*)p.h1, p.W2, p.U2, p.b2,
                            (__bf16*)p.h2, nullptr, p.flags, wg - 16, smem);
  else if (wg < 40)
    layer_loop<128, 256, 3>(nullptr, (const __bf16*)p.h2, p.W3, p.U3, p.b3,
                            (__bf16*)p.h3, nullptr, p.flags, wg - 24, smem);
  else
    layer_loop<256, 256, 4>(nullptr, (const __bf16*)p.h3, p.W4, p.U4, p.b4,
                            (__bf16*)p.h4, p.out, p.flags, wg - 40, smem);
}

extern "C" void kernel_launch(void* const* d_in, const int* in_sizes, int n_in,
                              void* d_out, int out_size, void* d_ws, size_t ws_size,
                              hipStream_t stream) {
  unsigned char* ws = (unsigned char*)d_ws;
  KParams p;
  p.x  = (const float*)d_in[0];
  p.W1 = (const float*)d_in[1];  p.U1 = (const float*)d_in[2];  p.b1 = (const float*)d_in[3];
  p.W2 = (const float*)d_in[4];  p.U2 = (const float*)d_in[5];  p.b2 = (const float*)d_in[6];
  p.W3 = (const float*)d_in[7];  p.U3 = (const float*)d_in[8];  p.b3 = (const float*)d_in[9];
  p.W4 = (const float*)d_in[10]; p.U4 = (const float*)d_in[11]; p.b4 = (const float*)d_in[12];
  p.out = (float*)d_out;
  p.flags = (unsigned*)ws;                 // 4 packed flag lines (512 B used)
  size_t off = 8192;
  p.h1 = (void*)(ws + off); off += (size_t)2 * 64 * 256 * 2;
  p.h2 = (void*)(ws + off); off += (size_t)2 * 64 * 128 * 2;
  p.h3 = (void*)(ws + off); off += (size_t)2 * 64 * 256 * 2;
  p.h4 = (void*)(ws + off);

  hipMemsetAsync(d_ws, 0, 8192, stream);   // zero the step flags

  lstm_kernel<<<dim3(NWG), dim3(256), 0, stream>>>(p);
}